// Round 6
// baseline (2425.449 us; speedup 1.0000x reference)
//
#include <hip/hip_runtime.h>
#include <hip/hip_bf16.h>

#define SEQ 1024
#define HDIM 2048
#define NHEADS 16
#define KVHEADS 8
#define HEADD 128
#define QKHEADS 24
#define DFFN 6144
#define VOCAB 32000
#define QKVO 4096   // (QKH+KVH)*HD

typedef __attribute__((ext_vector_type(8))) short bh8;
typedef __attribute__((ext_vector_type(4))) float f4v;

// ---------- bf16 split helpers ----------
__device__ __forceinline__ unsigned short f2bf_rn(float x) {
  unsigned int u = __float_as_uint(x);
  u += 0x7fffu + ((u >> 16) & 1u);
  return (unsigned short)(u >> 16);
}
__device__ __forceinline__ float bf2f(unsigned short h) {
  return __uint_as_float(((unsigned int)h) << 16);
}

// ---------------- fp32 -> (hi, lo) bf16 split, vectorized ----------------
__global__ __launch_bounds__(256) void split_bf_k(const float* __restrict__ in,
                                                  unsigned short* __restrict__ hi,
                                                  unsigned short* __restrict__ lo,
                                                  int n4) {
  for (int i = blockIdx.x * 256 + threadIdx.x; i < n4; i += gridDim.x * 256) {
    const float4 v = ((const float4*)in)[i];
    ushort4 h, l;
    h.x = f2bf_rn(v.x); l.x = f2bf_rn(v.x - bf2f(h.x));
    h.y = f2bf_rn(v.y); l.y = f2bf_rn(v.y - bf2f(h.y));
    h.z = f2bf_rn(v.z); l.z = f2bf_rn(v.z - bf2f(h.z));
    h.w = f2bf_rn(v.w); l.w = f2bf_rn(v.w - bf2f(h.w));
    ((ushort4*)hi)[i] = h;
    ((ushort4*)lo)[i] = l;
  }
}

// ---------------- async global->LDS 16B helpers ----------------
#if defined(__has_builtin)
#if __has_builtin(__builtin_amdgcn_global_load_lds)
#define HAVE_GLOAD_LDS 1
#endif
#endif

#ifdef HAVE_GLOAD_LDS
__device__ __forceinline__ void gload16(const unsigned short* g, unsigned short* l) {
  __builtin_amdgcn_global_load_lds(
      (const __attribute__((address_space(1))) unsigned int*)g,
      (__attribute__((address_space(3))) unsigned int*)l, 16, 0, 0);
}
__device__ __forceinline__ void gload16f(const float* g, float* l) {
  __builtin_amdgcn_global_load_lds(
      (const __attribute__((address_space(1))) unsigned int*)g,
      (__attribute__((address_space(3))) unsigned int*)l, 16, 0, 0);
}
#endif

// ---------------- split-bf16 MFMA GEMM: C[M][N] = A[M][K]*B[N][K]^T ----------
// 128x128 tile, 4 waves 2x2 (wave tile 64x64), 16x16x32 bf16 MFMA, 3-term split.
// XCD-aware bijective block swizzle (m204): same-XCD blocks sweep bx within one
// by-row so each XCD's private L2 holds a single A-panel.
__global__ __launch_bounds__(256) void gemm128_k(
    const unsigned short* __restrict__ Ah, const unsigned short* __restrict__ Al,
    const unsigned short* __restrict__ Bh, const unsigned short* __restrict__ Bl,
    float* __restrict__ C, int N, int ldK, int Ksub) {
  __shared__ __align__(16) unsigned short As_h[128 * 32];
  __shared__ __align__(16) unsigned short As_l[128 * 32];
  __shared__ __align__(16) unsigned short Bs_h[128 * 32];
  __shared__ __align__(16) unsigned short Bs_l[128 * 32];
  const int tid = threadIdx.x;
  const int lane = tid & 63;
  const int w = tid >> 6;
  const int wr = w >> 1, wc = w & 1;

  // ---- XCD bijective swizzle of the linear block id ----
  const int gx = gridDim.x, gy = gridDim.y;
  const int nwg = gx * gy * gridDim.z;
  const int orig = blockIdx.x + gx * (blockIdx.y + gy * blockIdx.z);
  const int qv = nwg >> 3, rm = nwg & 7;
  const int xcd = orig & 7, idx = orig >> 3;
  const int wgid = (xcd < rm ? xcd * (qv + 1) : rm * (qv + 1) + (xcd - rm) * qv) + idx;
  const int bx = wgid % gx;
  const int by = (wgid / gx) % gy;
  const int bz = wgid / (gx * gy);
  const int bm = by * 128, bn = bx * 128;
  const int kbase = bz * Ksub;
  C += (size_t)bz * SEQ * N;

  f4v acc[4][4];
  const f4v zero = {0.f, 0.f, 0.f, 0.f};
  #pragma unroll
  for (int mi = 0; mi < 4; ++mi)
    #pragma unroll
    for (int ni = 0; ni < 4; ++ni) acc[mi][ni] = zero;

  // chunk c (0..511): 16B at LDS byte offset c*16; global row bm|bn + (c>>2), k-col (c&3)*8
  const int c0 = tid, c1 = tid + 256;
  const size_t ga0 = (size_t)(bm + (c0 >> 2)) * ldK + kbase + (c0 & 3) * 8;
  const size_t ga1 = (size_t)(bm + (c1 >> 2)) * ldK + kbase + (c1 & 3) * 8;
  const size_t gb0 = (size_t)(bn + (c0 >> 2)) * ldK + kbase + (c0 & 3) * 8;
  const size_t gb1 = (size_t)(bn + (c1 >> 2)) * ldK + kbase + (c1 & 3) * 8;
  const int l0 = (w * 64) * 8;        // shorts; wave-uniform base, HW adds lane*16B
  const int l1 = (w * 64 + 256) * 8;

  for (int k0 = 0; k0 < Ksub; k0 += 32) {
    __syncthreads();
#ifdef HAVE_GLOAD_LDS
    gload16(Ah + ga0 + k0, As_h + l0);
    gload16(Al + ga0 + k0, As_l + l0);
    gload16(Ah + ga1 + k0, As_h + l1);
    gload16(Al + ga1 + k0, As_l + l1);
    gload16(Bh + gb0 + k0, Bs_h + l0);
    gload16(Bl + gb0 + k0, Bs_l + l0);
    gload16(Bh + gb1 + k0, Bs_h + l1);
    gload16(Bl + gb1 + k0, Bs_l + l1);
#else
    {
      const bh8 a0 = *(const bh8*)(Ah + ga0 + k0), a0l = *(const bh8*)(Al + ga0 + k0);
      const bh8 a1 = *(const bh8*)(Ah + ga1 + k0), a1l = *(const bh8*)(Al + ga1 + k0);
      const bh8 b0 = *(const bh8*)(Bh + gb0 + k0), b0l = *(const bh8*)(Bl + gb0 + k0);
      const bh8 b1 = *(const bh8*)(Bh + gb1 + k0), b1l = *(const bh8*)(Bl + gb1 + k0);
      *(bh8*)(As_h + c0 * 8) = a0; *(bh8*)(As_l + c0 * 8) = a0l;
      *(bh8*)(As_h + c1 * 8) = a1; *(bh8*)(As_l + c1 * 8) = a1l;
      *(bh8*)(Bs_h + c0 * 8) = b0; *(bh8*)(Bs_l + c0 * 8) = b0l;
      *(bh8*)(Bs_h + c1 * 8) = b1; *(bh8*)(Bs_l + c1 * 8) = b1l;
    }
#endif
    __syncthreads();
    const int ko8 = (lane >> 4) * 8;
    bh8 ah[4], al[4];
    #pragma unroll
    for (int mi = 0; mi < 4; ++mi) {
      const int r = wr * 64 + mi * 16 + (lane & 15);
      ah[mi] = *(const bh8*)(As_h + r * 32 + ko8);
      al[mi] = *(const bh8*)(As_l + r * 32 + ko8);
    }
    #pragma unroll
    for (int ni = 0; ni < 4; ++ni) {
      const int cix = wc * 64 + ni * 16 + (lane & 15);
      const bh8 bh = *(const bh8*)(Bs_h + cix * 32 + ko8);
      const bh8 bl = *(const bh8*)(Bs_l + cix * 32 + ko8);
      #pragma unroll
      for (int mi = 0; mi < 4; ++mi) {
        f4v t = acc[mi][ni];
        t = __builtin_amdgcn_mfma_f32_16x16x32_bf16(al[mi], bh, t, 0, 0, 0);
        t = __builtin_amdgcn_mfma_f32_16x16x32_bf16(ah[mi], bl, t, 0, 0, 0);
        t = __builtin_amdgcn_mfma_f32_16x16x32_bf16(ah[mi], bh, t, 0, 0, 0);
        acc[mi][ni] = t;
      }
    }
  }
  // epilogue: C/D layout col=lane&15, row=(lane>>4)*4+j (m89-verified)
  #pragma unroll
  for (int mi = 0; mi < 4; ++mi) {
    #pragma unroll
    for (int ni = 0; ni < 4; ++ni) {
      const int r0 = bm + wr * 64 + mi * 16 + (lane >> 4) * 4;
      const int cc = bn + wc * 64 + ni * 16 + (lane & 15);
      #pragma unroll
      for (int j = 0; j < 4; ++j)
        C[(size_t)(r0 + j) * N + cc] = acc[mi][ni][j];
    }
  }
}

// ---------------- out = p0 + p1 + resid ----------------
__global__ __launch_bounds__(256) void add2_resid_k(const float* __restrict__ p0,
                                                    const float* __restrict__ p1,
                                                    const float* __restrict__ resid,
                                                    float* __restrict__ out) {
  const int i = blockIdx.x * 256 + threadIdx.x;
  const float4 a = ((const float4*)p0)[i];
  const float4 b = ((const float4*)p1)[i];
  const float4 r = ((const float4*)resid)[i];
  float4 o;
  o.x = a.x + b.x + r.x; o.y = a.y + b.y + r.y;
  o.z = a.z + b.z + r.z; o.w = a.w + b.w + r.w;
  ((float4*)out)[i] = o;
}

// ---------------- l2norm rows [rows][2048] -> f32 out ----------------
__global__ __launch_bounds__(256) void l2norm_rows_k(const float* __restrict__ in,
                                                     float* __restrict__ out) {
  __shared__ float red[4];
  const int row = blockIdx.x;
  const int t = threadIdx.x;
  const float4* ip = (const float4*)(in + (size_t)row * HDIM);
  float4 a = ip[t];
  float4 b = ip[t + 256];
  float ss = a.x*a.x + a.y*a.y + a.z*a.z + a.w*a.w
           + b.x*b.x + b.y*b.y + b.z*b.z + b.w*b.w;
  #pragma unroll
  for (int off = 32; off; off >>= 1) ss += __shfl_xor(ss, off, 64);
  if ((t & 63) == 0) red[t >> 6] = ss;
  __syncthreads();
  const float sc = rsqrtf(red[0] + red[1] + red[2] + red[3]);
  float4* op = (float4*)(out + (size_t)row * HDIM);
  a.x *= sc; a.y *= sc; a.z *= sc; a.w *= sc;
  b.x *= sc; b.y *= sc; b.z *= sc; b.w *= sc;
  op[t] = a;
  op[t + 256] = b;
}

// ---------------- l2norm rows -> bf16 hi/lo split (fast path, fused) ------------
__global__ __launch_bounds__(256) void l2norm_split_k(const float* __restrict__ in,
                                                      unsigned short* __restrict__ hi,
                                                      unsigned short* __restrict__ lo) {
  __shared__ float red[4];
  const int row = blockIdx.x;
  const int t = threadIdx.x;
  const float4* ip = (const float4*)(in + (size_t)row * HDIM);
  float4 a = ip[t];
  float4 b = ip[t + 256];
  float ss = a.x*a.x + a.y*a.y + a.z*a.z + a.w*a.w
           + b.x*b.x + b.y*b.y + b.z*b.z + b.w*b.w;
  #pragma unroll
  for (int off = 32; off; off >>= 1) ss += __shfl_xor(ss, off, 64);
  if ((t & 63) == 0) red[t >> 6] = ss;
  __syncthreads();
  const float sc = rsqrtf(red[0] + red[1] + red[2] + red[3]);
  a.x *= sc; a.y *= sc; a.z *= sc; a.w *= sc;
  b.x *= sc; b.y *= sc; b.z *= sc; b.w *= sc;
  ushort4 ha, la, hb, lb;
  ha.x = f2bf_rn(a.x); la.x = f2bf_rn(a.x - bf2f(ha.x));
  ha.y = f2bf_rn(a.y); la.y = f2bf_rn(a.y - bf2f(ha.y));
  ha.z = f2bf_rn(a.z); la.z = f2bf_rn(a.z - bf2f(ha.z));
  ha.w = f2bf_rn(a.w); la.w = f2bf_rn(a.w - bf2f(ha.w));
  hb.x = f2bf_rn(b.x); lb.x = f2bf_rn(b.x - bf2f(hb.x));
  hb.y = f2bf_rn(b.y); lb.y = f2bf_rn(b.y - bf2f(hb.y));
  hb.z = f2bf_rn(b.z); lb.z = f2bf_rn(b.z - bf2f(hb.z));
  hb.w = f2bf_rn(b.w); lb.w = f2bf_rn(b.w - bf2f(hb.w));
  ((ushort4*)(hi + (size_t)row * HDIM))[t] = ha;
  ((ushort4*)(hi + (size_t)row * HDIM))[t + 256] = hb;
  ((ushort4*)(lo + (size_t)row * HDIM))[t] = la;
  ((ushort4*)(lo + (size_t)row * HDIM))[t + 256] = lb;
}

// ---------------- fp32 fallback NT GEMM ----------------
__global__ __launch_bounds__(256) void gemm_nt64_k(const float* __restrict__ A,
                                                   const float* __restrict__ B,
                                                   const float* __restrict__ add,
                                                   float* __restrict__ C,
                                                   int M, int N, int K) {
  __shared__ __align__(16) float As[16][68];
  __shared__ __align__(16) float Bs[16][68];
  const int bm = blockIdx.y * 64;
  const int bn = blockIdx.x * 64;
  const int tid = threadIdx.x;
  const int lr = tid >> 2;
  const int lk = (tid & 3) * 4;
  const int tm = (tid >> 4) * 4;
  const int tn = (tid & 15) * 4;
  float acc[4][4] = {};
  const float* ap = A + (size_t)(bm + lr) * K + lk;
  const float* bp = B + (size_t)(bn + lr) * K + lk;
  for (int k0 = 0; k0 < K; k0 += 16) {
    const float4 av = *(const float4*)(ap + k0);
    const float4 bv = *(const float4*)(bp + k0);
    __syncthreads();
    As[lk + 0][lr] = av.x; As[lk + 1][lr] = av.y;
    As[lk + 2][lr] = av.z; As[lk + 3][lr] = av.w;
    Bs[lk + 0][lr] = bv.x; Bs[lk + 1][lr] = bv.y;
    Bs[lk + 2][lr] = bv.z; Bs[lk + 3][lr] = bv.w;
    __syncthreads();
    #pragma unroll
    for (int kk = 0; kk < 16; ++kk) {
      const float4 a = *(const float4*)&As[kk][tm];
      const float4 b = *(const float4*)&Bs[kk][tn];
      acc[0][0] += a.x*b.x; acc[0][1] += a.x*b.y; acc[0][2] += a.x*b.z; acc[0][3] += a.x*b.w;
      acc[1][0] += a.y*b.x; acc[1][1] += a.y*b.y; acc[1][2] += a.y*b.z; acc[1][3] += a.y*b.w;
      acc[2][0] += a.z*b.x; acc[2][1] += a.z*b.y; acc[2][2] += a.z*b.z; acc[2][3] += a.z*b.w;
      acc[3][0] += a.w*b.x; acc[3][1] += a.w*b.y; acc[3][2] += a.w*b.z; acc[3][3] += a.w*b.w;
    }
  }
  #pragma unroll
  for (int i = 0; i < 4; ++i) {
    const int r = bm + tm + i;
    float4 o;
    o.x = acc[i][0]; o.y = acc[i][1]; o.z = acc[i][2]; o.w = acc[i][3];
    if (add) {
      const float4 av = *(const float4*)(add + (size_t)r * N + bn + tn);
      o.x += av.x; o.y += av.y; o.z += av.z; o.w += av.w;
    }
    *(float4*)(C + (size_t)r * N + bn + tn) = o;
  }
}

// ---------------- per-(token,head) l2norm * w then RoPE, in-place ----------------
__global__ __launch_bounds__(128) void qknorm_rope_k(float* __restrict__ qkv,
                                                     const float* __restrict__ w,
                                                     const float* __restrict__ cosb,
                                                     const float* __restrict__ sinb) {
  __shared__ float sm[128];
  __shared__ float red[2];
  const int s = blockIdx.x;
  const int h = blockIdx.y;
  const int t = threadIdx.x;
  float* p = qkv + (size_t)s * QKVO + h * HEADD;
  const float v = p[t];
  float ss = v * v;
  #pragma unroll
  for (int off = 32; off; off >>= 1) ss += __shfl_xor(ss, off, 64);
  if ((t & 63) == 0) red[t >> 6] = ss;
  __syncthreads();
  const float norm = rsqrtf(red[0] + red[1]);
  const float y = v * norm * w[h * HEADD + t];
  sm[t] = y;
  __syncthreads();
  const float rot = sm[t ^ 64];
  p[t] = y * cosb[s * HEADD + t] + rot * sinb[s * HEADD + t];
}

// ---------------- tiled attention (fast path): q-tile 32, j-tile 64 --------------
// grid (SEQ/32, NHEADS), 256 thr. LDS: Q 16KB + K 32KB (XOR-swizzled) + V 32KB.
// Output: bf16 hi/lo split of attention out, written to [SEQ][2048] (o-proj A).
__global__ __launch_bounds__(256) void attn_tiled_k(const float* __restrict__ qkv,
                                                    unsigned short* __restrict__ ohi,
                                                    unsigned short* __restrict__ olo) {
  __shared__ __align__(16) float Qs[32][128];   // 16KB
  __shared__ __align__(16) float Ks[64 * 128];  // 32KB, swizzled rows
  __shared__ __align__(16) float Vs[64][128];   // 32KB
  const int tid = threadIdx.x, lane = tid & 63, w = tid >> 6;
  const int qt = blockIdx.x, h = blockIdx.y, kh = h >> 1;
  const int qbase = qt * 32;

  // ---- stage Q once: 1024 x 16B chunks, 32 chunks/row; wave-uniform LDS base ----
  #pragma unroll
  for (int r = 0; r < 4; ++r) {
    const int chunk = tid + r * 256;           // this lane's chunk; LDS byte off = chunk*16
    const int qq = chunk >> 5, c16 = chunk & 31;
    const float* g = qkv + (size_t)(qbase + qq) * QKVO + h * HEADD + c16 * 4;
#ifdef HAVE_GLOAD_LDS
    float* lbase = &Qs[0][0] + (r * 256 + w * 64) * 4;  // wave-uniform; HW adds lane*16B
    gload16f(g, lbase);
#else
    *(float4*)&Qs[qq][c16 * 4] = *(const float4*)g;
#endif
  }

  float m[8], ll[8], o0[8], o1[8], p[8];
  #pragma unroll
  for (int i = 0; i < 8; ++i) { m[i] = -3.0e38f; ll[i] = 0.f; o0[i] = 0.f; o1[i] = 0.f; }

  const int kx = (lane & 31) << 4;             // score-read swizzle
  const int kj = tid >> 2;                     // staging row 0..63
  const int kwx = (kj & 31) << 4;              // staging-write swizzle
  const int jtmax = (qbase + 31) >> 6;

  for (int jt = 0; jt <= jtmax; ++jt) {
    const int j0 = jt * 64;
    __syncthreads();   // previous tile fully consumed (also drains Q gload on jt==0)
    // ---- stage K (reg -> swizzled LDS): thread covers 32 d of one row ----
    {
      const float* kg = qkv + (size_t)(j0 + kj) * QKVO + 2048 + kh * HEADD + (tid & 3) * 32;
      char* kw = (char*)Ks + kj * 512;
      #pragma unroll
      for (int c = 0; c < 8; ++c) {
        const float4 kv = *(const float4*)(kg + c * 4);
        *(float4*)(kw + (((tid & 3) * 128 + c * 16) ^ kwx)) = kv;
      }
    }
    // ---- stage V (linear, async): 2048 chunks, 32/row; wave-uniform LDS base ----
    #pragma unroll
    for (int r = 0; r < 8; ++r) {
      const int chunk = tid + r * 256;         // LDS byte off = chunk*16
      const int vj = chunk >> 5, c16 = chunk & 31;
      const float* g = qkv + (size_t)(j0 + vj) * QKVO + 3072 + kh * HEADD + c16 * 4;
#ifdef HAVE_GLOAD_LDS
      float* lbase = &Vs[0][0] + (r * 256 + w * 64) * 4;  // wave-uniform; HW adds lane*16B
      gload16f(g, lbase);
#else
      *(float4*)&Vs[vj][c16 * 4] = *(const float4*)g;
#endif
    }
    __syncthreads();   // staging visible (vmcnt+lgkm drained by barrier semantics)

    // ---- scores: lane = j, 8 q-rows per wave ----
    float s[8] = {0.f,0.f,0.f,0.f,0.f,0.f,0.f,0.f};
    const char* kb = (const char*)Ks + lane * 512;
    #pragma unroll
    for (int dblk = 0; dblk < 4; ++dblk) {
      float4 kk[8];
      #pragma unroll
      for (int c = 0; c < 8; ++c)
        kk[c] = *(const float4*)(kb + ((dblk * 128 + c * 16) ^ kx));
      #pragma unroll
      for (int qq = 0; qq < 8; ++qq) {
        const float* qrow = &Qs[w * 8 + qq][dblk * 32];
        #pragma unroll
        for (int c = 0; c < 8; ++c) {
          const float4 qv = *(const float4*)(qrow + c * 4);
          s[qq] += qv.x * kk[c].x + qv.y * kk[c].y + qv.z * kk[c].z + qv.w * kk[c].w;
        }
      }
    }

    // ---- mask + online softmax (per q-row, wave-wide) ----
    const int jg = j0 + lane;
    #pragma unroll
    for (int qq = 0; qq < 8; ++qq) {
      const int qg = qbase + w * 8 + qq;
      const float sv = (jg <= qg) ? s[qq] : -3.0e38f;
      float tm = sv;
      #pragma unroll
      for (int off = 32; off; off >>= 1) tm = fmaxf(tm, __shfl_xor(tm, off, 64));
      const float mn = fmaxf(m[qq], tm);
      const float sc = __expf(m[qq] - mn);
      const float pv = __expf(sv - mn);
      float ps = pv;
      #pragma unroll
      for (int off = 32; off; off >>= 1) ps += __shfl_xor(ps, off, 64);
      ll[qq] = ll[qq] * sc + ps;
      o0[qq] *= sc; o1[qq] *= sc;
      m[qq] = mn;
      p[qq] = pv;
    }

    // ---- PV: lane = d (d and d+64), p broadcast via shfl ----
    #pragma unroll 4
    for (int j = 0; j < 64; ++j) {
      const float v0 = Vs[j][lane];
      const float v1 = Vs[j][64 + lane];
      #pragma unroll
      for (int qq = 0; qq < 8; ++qq) {
        const float pj = __shfl(p[qq], j, 64);
        o0[qq] += pj * v0;
        o1[qq] += pj * v1;
      }
    }
  }

  // ---- epilogue: normalize + bf16 hi/lo split write ----
  #pragma unroll
  for (int qq = 0; qq < 8; ++qq) {
    const float inv = 1.f / ll[qq];
    const int row = qbase + w * 8 + qq;
    unsigned short* ph = ohi + (size_t)row * HDIM + h * HEADD;
    unsigned short* pl = olo + (size_t)row * HDIM + h * HEADD;
    const float v0 = o0[qq] * inv, v1 = o1[qq] * inv;
    const unsigned short h0 = f2bf_rn(v0);
    const unsigned short h1 = f2bf_rn(v1);
    ph[lane]      = h0; pl[lane]      = f2bf_rn(v0 - bf2f(h0));
    ph[64 + lane] = h1; pl[64 + lane] = f2bf_rn(v1 - bf2f(h1));
  }
}

// ---------------- flash attention (fallback) ----------------
__global__ __launch_bounds__(64) void attn_flash_k(const float* __restrict__ qkv,
                                                   float* __restrict__ out) {
  const int q = blockIdx.x;
  const int h = blockIdx.y;
  const int lane = threadIdx.x;
  const float2 qv = *(const float2*)(qkv + (size_t)q * QKVO + h * HEADD + lane * 2);
  const float* kbase = qkv + (size_t)(NHEADS * HEADD) + (h >> 1) * HEADD + lane * 2;
  const float* vbase = kbase + KVHEADS * HEADD;
  float m = -3.0e38f, d = 0.f, acc0 = 0.f, acc1 = 0.f;
  for (int j = 0; j <= q; ++j) {
    const float2 kv = *(const float2*)(kbase + (size_t)j * QKVO);
    float s = qv.x * kv.x + qv.y * kv.y;
    #pragma unroll
    for (int off = 32; off; off >>= 1) s += __shfl_xor(s, off, 64);
    const float mn = fmaxf(m, s);
    const float scale = __expf(m - mn);
    const float pe = __expf(s - mn);
    const float2 vv = *(const float2*)(vbase + (size_t)j * QKVO);
    d = d * scale + pe;
    acc0 = acc0 * scale + pe * vv.x;
    acc1 = acc1 * scale + pe * vv.y;
    m = mn;
  }
  const float inv = 1.f / d;
  float* op = out + (size_t)q * HDIM + h * HEADD + lane * 2;
  op[0] = acc0 * inv;
  op[1] = acc1 * inv;
}

// ---------------- silu(gate)*up -> f32 (fallback) ----------------
__global__ __launch_bounds__(256) void silu_mul_k(const float* __restrict__ gu,
                                                  float* __restrict__ act) {
  const int i = blockIdx.x * 256 + threadIdx.x;
  const int s = i / (DFFN / 4);
  const int f = i % (DFFN / 4);
  const float4 g = *(const float4*)(gu + (size_t)s * (2 * DFFN) + f * 4);
  const float4 u = *(const float4*)(gu + (size_t)s * (2 * DFFN) + DFFN + f * 4);
  float4 o;
  o.x = g.x / (1.f + __expf(-g.x)) * u.x;
  o.y = g.y / (1.f + __expf(-g.y)) * u.y;
  o.z = g.z / (1.f + __expf(-g.z)) * u.z;
  o.w = g.w / (1.f + __expf(-g.w)) * u.w;
  *(float4*)(act + (size_t)i * 4) = o;
}

// ---------------- silu(gate)*up -> bf16 hi/lo split (fast path) ----------------
__global__ __launch_bounds__(256) void silu_split_k(const float* __restrict__ gu,
                                                    unsigned short* __restrict__ hi,
                                                    unsigned short* __restrict__ lo) {
  const int i = blockIdx.x * 256 + threadIdx.x;
  const int s = i / (DFFN / 4);
  const int f = i % (DFFN / 4);
  const float4 g = *(const float4*)(gu + (size_t)s * (2 * DFFN) + f * 4);
  const float4 u = *(const float4*)(gu + (size_t)s * (2 * DFFN) + DFFN + f * 4);
  float4 o;
  o.x = g.x / (1.f + __expf(-g.x)) * u.x;
  o.y = g.y / (1.f + __expf(-g.y)) * u.y;
  o.z = g.z / (1.f + __expf(-g.z)) * u.z;
  o.w = g.w / (1.f + __expf(-g.w)) * u.w;
  ushort4 hh, lv;
  hh.x = f2bf_rn(o.x); lv.x = f2bf_rn(o.x - bf2f(hh.x));
  hh.y = f2bf_rn(o.y); lv.y = f2bf_rn(o.y - bf2f(hh.y));
  hh.z = f2bf_rn(o.z); lv.z = f2bf_rn(o.z - bf2f(hh.z));
  hh.w = f2bf_rn(o.w); lv.w = f2bf_rn(o.w - bf2f(hh.w));
  ((ushort4*)hi)[i] = hh;
  ((ushort4*)lo)[i] = lv;
}

// ---------------- lm_head matvec ----------------
__global__ __launch_bounds__(256) void lm_head_k(const float* __restrict__ v,
                                                 const float* __restrict__ W,
                                                 float* __restrict__ out) {
  const int row = blockIdx.x * 4 + (threadIdx.x >> 6);
  const int lane = threadIdx.x & 63;
  const float4* wp = (const float4*)(W + (size_t)row * HDIM);
  const float4* vp = (const float4*)v;
  float s = 0.f;
  #pragma unroll
  for (int i = 0; i < 8; ++i) {
    const float4 w = wp[i * 64 + lane];
    const float4 x = vp[i * 64 + lane];
    s += w.x*x.x + w.y*x.y + w.z*x.z + w.w*x.w;
  }
  #pragma unroll
  for (int off = 32; off; off >>= 1) s += __shfl_xor(s, off, 64);
  if (lane == 0) out[row] = s;
}

static inline int sgrid(int n4) { int b = (n4 + 255) / 256; return b > 2048 ? 2048 : b; }

extern "C" void kernel_launch(void* const* d_in, const int* in_sizes, int n_in,
                              void* d_out, int out_size, void* d_ws, size_t ws_size,
                              hipStream_t stream) {
  const float* hidden    = (const float*)d_in[0];
  const float* qkv_w     = (const float*)d_in[1];
  const float* qk_norm_w = (const float*)d_in[2];
  const float* o_w       = (const float*)d_in[3];
  const float* gate_up_w = (const float*)d_in[4];
  const float* down_w    = (const float*)d_in[5];
  const float* lm_head_w = (const float*)d_in[6];
  const float* cosb      = (const float*)d_in[7];
  const float* sinb      = (const float*)d_in[8];

  float* ws    = (float*)d_ws;
  float* hn    = ws;                       // 2,097,152 f32 (fallback only)
  float* qkvb  = hn   + 2097152;           // 4,194,304
  float* attno = qkvb + 4194304;           // 2,097,152 (fallback only)
  float* xb    = attno + 2097152;          // 2,097,152
  float* gu    = xb   + 2097152;           // 12,582,912
  float* lastn = gu   + 12582912;          // 2048
  float* act   = qkvb;                     // fallback alias
  float* p0    = gu;                       // split-K partials alias dead gu region
  float* p1    = gu + 2097152;

  unsigned short* w_hi = (unsigned short*)(lastn + 2048);
  unsigned short* w_lo = w_hi + 100663296;
  unsigned short* a_hi = w_lo + 100663296;
  unsigned short* a_lo = a_hi + 6291456;
  const size_t need = (size_t)((char*)(a_lo + 6291456) - (char*)d_ws);

  if (ws_size >= need) {
    // -------- fast path: split-bf16 MFMA GEMMs + tiled attention --------
    split_bf_k<<<sgrid(4194304), 256, 0, stream>>>(qkv_w,     w_hi,            w_lo,            4194304);
    split_bf_k<<<sgrid(2097152), 256, 0, stream>>>(o_w,       w_hi + 16777216, w_lo + 16777216, 2097152);
    split_bf_k<<<sgrid(12582912),256, 0, stream>>>(gate_up_w, w_hi + 25165824, w_lo + 25165824, 12582912);
    split_bf_k<<<sgrid(6291456), 256, 0, stream>>>(down_w,    w_hi + 75497472, w_lo + 75497472, 6291456);

    for (int l = 0; l < 2; ++l) {
      const float* xin = (l == 0) ? hidden : xb;
      const size_t qkvOff = (size_t)l * 8388608;
      const size_t oOff   = 16777216 + (size_t)l * 4194304;
      const size_t guOff  = 25165824 + (size_t)l * 25165824;
      const size_t dnOff  = 75497472 + (size_t)l * 12582912;

      // ---- attention block ----
      l2norm_split_k<<<SEQ, 256, 0, stream>>>(xin, a_hi, a_lo);
      gemm128_k<<<dim3(QKVO/128, SEQ/128, 1), 256, 0, stream>>>(
          a_hi, a_lo, w_hi + qkvOff, w_lo + qkvOff, qkvb, QKVO, HDIM, HDIM);
      qknorm_rope_k<<<dim3(SEQ, QKHEADS), 128, 0, stream>>>(
          qkvb, qk_norm_w + (size_t)l * QKHEADS * HEADD, cosb, sinb);
      attn_tiled_k<<<dim3(SEQ/32, NHEADS), 256, 0, stream>>>(qkvb, a_hi, a_lo);
      gemm128_k<<<dim3(HDIM/128, SEQ/128, 2), 256, 0, stream>>>(
          a_hi, a_lo, w_hi + oOff, w_lo + oOff, p0, HDIM, HDIM, HDIM/2);
      add2_resid_k<<<2048, 256, 0, stream>>>(p0, p1, xin, xb);

      // ---- mlp block ----
      l2norm_split_k<<<SEQ, 256, 0, stream>>>(xb, a_hi, a_lo);
      gemm128_k<<<dim3(2*DFFN/128, SEQ/128, 1), 256, 0, stream>>>(
          a_hi, a_lo, w_hi + guOff, w_lo + guOff, gu, 2*DFFN, HDIM, HDIM);
      silu_split_k<<<(SEQ * DFFN / 4) / 256, 256, 0, stream>>>(gu, a_hi, a_lo);
      gemm128_k<<<dim3(HDIM/128, SEQ/128, 2), 256, 0, stream>>>(
          a_hi, a_lo, w_hi + dnOff, w_lo + dnOff, p0, HDIM, DFFN, DFFN/2);
      add2_resid_k<<<2048, 256, 0, stream>>>(p0, p1, xb, xb);
    }
  } else {
    // -------- fallback: fp32 vector path --------
    for (int l = 0; l < 2; ++l) {
      const float* xin = (l == 0) ? hidden : xb;
      l2norm_rows_k<<<SEQ, 256, 0, stream>>>(xin, hn);
      gemm_nt64_k<<<dim3(QKVO / 64, SEQ / 64), 256, 0, stream>>>(
          hn, qkv_w + (size_t)l * QKVO * HDIM, nullptr, qkvb, SEQ, QKVO, HDIM);
      qknorm_rope_k<<<dim3(SEQ, QKHEADS), 128, 0, stream>>>(
          qkvb, qk_norm_w + (size_t)l * QKHEADS * HEADD, cosb, sinb);
      attn_flash_k<<<dim3(SEQ, NHEADS), 64, 0, stream>>>(qkvb, attno);
      gemm_nt64_k<<<dim3(HDIM / 64, SEQ / 64), 256, 0, stream>>>(
          attno, o_w + (size_t)l * HDIM * HDIM, xin, xb, SEQ, HDIM, HDIM);
      l2norm_rows_k<<<SEQ, 256, 0, stream>>>(xb, hn);
      gemm_nt64_k<<<dim3(2 * DFFN / 64, SEQ / 64), 256, 0, stream>>>(
          hn, gate_up_w + (size_t)l * 2 * DFFN * HDIM, nullptr, gu, SEQ, 2 * DFFN, HDIM);
      silu_mul_k<<<(SEQ * DFFN / 4) / 256, 256, 0, stream>>>(gu, act);
      gemm_nt64_k<<<dim3(HDIM / 64, SEQ / 64), 256, 0, stream>>>(
          act, down_w + (size_t)l * HDIM * DFFN, xb, xb, SEQ, HDIM, DFFN);
    }
  }
  l2norm_rows_k<<<1, 256, 0, stream>>>(xb + (size_t)(SEQ - 1) * HDIM, lastn);
  lm_head_k<<<VOCAB / 4, 256, 0, stream>>>(lastn, lm_head_w, (float*)d_out);
}